// Round 1
// baseline (8887.985 us; speedup 1.0000x reference)
//
#include <hip/hip_runtime.h>
#include <cmath>

typedef __bf16 bf16;
typedef float f32x4 __attribute__((ext_vector_type(4)));
typedef bf16 bf16x8 __attribute__((ext_vector_type(8)));

#define DEVINL __device__ __forceinline__

DEVINL void gload_lds16(const void* g, void* l) {
  __builtin_amdgcn_global_load_lds(
      (const __attribute__((address_space(1))) void*)g,
      (__attribute__((address_space(3))) void*)l, 16, 0, 0);
}

DEVINL float sigf(float x) { return 1.f / (1.f + __expf(-x)); }

// ---------------- cast / prep kernels ----------------
__global__ void cast_bf_k(const float* __restrict__ in, bf16* __restrict__ out, int n) {
  int i = blockIdx.x * blockDim.x + threadIdx.x;
  if (i < n) out[i] = (bf16)in[i];
}

// x: [B,T,I] f32 -> xe[t*B+b, i] bf16 ; xd = teacher-forced (shifted) tokens
__global__ void prep_x_k(const float* __restrict__ x, bf16* __restrict__ xe,
                         bf16* __restrict__ xd) {
  int idx = blockIdx.x * blockDim.x + threadIdx.x;  // over T*B*I = 4194304
  if (idx >= 128 * 64 * 512) return;
  int i = idx & 511;
  int b = (idx >> 9) & 63;
  int t = idx >> 15;
  xe[idx] = (bf16)x[(size_t)b * 65536 + (size_t)t * 512 + i];
  xd[idx] = (t == 0) ? (bf16)0.f
                     : (bf16)x[(size_t)b * 65536 + (size_t)(t - 1) * 512 + i];
}

__global__ void zero_state_k(bf16* hb, float* c, int n) {
  int i = blockIdx.x * blockDim.x + threadIdx.x;
  if (i < n) { hb[i] = (bf16)0.f; c[i] = 0.f; }
}
__global__ void tanh_save_k(const float* __restrict__ h, float* __restrict__ henc, int n) {
  int i = blockIdx.x * blockDim.x + threadIdx.x;
  if (i < n) henc[i] = tanhf(h[i]);
}
__global__ void dec_init_k(const float* __restrict__ henc, const float* __restrict__ c0,
                           bf16* __restrict__ hb, float* __restrict__ c, int n) {
  int i = blockIdx.x * blockDim.x + threadIdx.x;
  if (i < n) { hb[i] = (bf16)henc[i]; c[i] = c0[i]; }
}

// ---------------- big GEMM: C[M,N] = A[M,K] @ W[N,K]^T (all bf16, f32 accum) ---------
// mode 0: Cbf[row*N+col] = val
// mode 1: (FC) val = sigmoid(val + bias[col]); out[b*T*I + t*I + col], row = t*64+b
__global__ __launch_bounds__(256) void gemm_bt_k(
    const bf16* __restrict__ A, const bf16* __restrict__ Bw,
    bf16* __restrict__ Cbf, float* __restrict__ Cf32, const float* __restrict__ bias,
    int M, int N, int K, int mode) {
  __shared__ __attribute__((aligned(16))) bf16 As[128 * 32];
  __shared__ __attribute__((aligned(16))) bf16 Bs[128 * 32];
  const int tid = threadIdx.x;
  const int lane = tid & 63;
  const int wave = tid >> 6;
  const int wm = wave >> 1, wn = wave & 1;
  const int m0 = blockIdx.y * 128;
  const int n0 = blockIdx.x * 128;

  f32x4 acc[4][4];
  for (int i = 0; i < 4; ++i)
    for (int j = 0; j < 4; ++j) acc[i][j] = 0;

  const int r1 = tid >> 2;            // row 0..63 (chunk tid), +64 for chunk tid+256
  const int kc = (tid & 3) * 8;       // k element offset of 16B chunk
  const int fr = lane & 15;
  const int fk = (lane >> 4) * 8;

  for (int k0 = 0; k0 < K; k0 += 32) {
    gload_lds16(A + (size_t)(m0 + r1) * K + k0 + kc, As + tid * 8);
    gload_lds16(A + (size_t)(m0 + 64 + r1) * K + k0 + kc, As + 2048 + tid * 8);
    gload_lds16(Bw + (size_t)(n0 + r1) * K + k0 + kc, Bs + tid * 8);
    gload_lds16(Bw + (size_t)(n0 + 64 + r1) * K + k0 + kc, Bs + 2048 + tid * 8);
    __syncthreads();
    bf16x8 af[4], bw[4];
    for (int i = 0; i < 4; ++i)
      af[i] = *(const bf16x8*)(As + (wm * 64 + i * 16 + fr) * 32 + fk);
    for (int j = 0; j < 4; ++j)
      bw[j] = *(const bf16x8*)(Bs + (wn * 64 + j * 16 + fr) * 32 + fk);
    for (int i = 0; i < 4; ++i)
      for (int j = 0; j < 4; ++j)
        acc[i][j] = __builtin_amdgcn_mfma_f32_16x16x32_bf16(af[i], bw[j], acc[i][j], 0, 0, 0);
    __syncthreads();
  }

  const int col16 = lane & 15;
  const int rq = (lane >> 4) * 4;
  for (int i = 0; i < 4; ++i)
    for (int j = 0; j < 4; ++j)
      for (int r = 0; r < 4; ++r) {
        int row = m0 + wm * 64 + i * 16 + rq + r;
        int col = n0 + wn * 64 + j * 16 + col16;
        float v = acc[i][j][r];
        if (mode == 0) {
          Cbf[(size_t)row * N + col] = (bf16)v;
        } else {
          v = sigf(v + bias[col]);
          int b = row & 63, t = row >> 6;
          Cf32[(size_t)b * (128 * 512) + (size_t)t * 512 + col] = v;
        }
      }
}

// ---------------- fused LSTM step: gates = Gt + h@Whh^T + b, then cell ----------------
// grid 128 WGs; WG owns hidden cols j0..j0+7 across all 4 gates (output cols n =
// gate*1024 + j0 + jj). Output tile 64(batch) x 32(4 gates x 8). K = 1024.
__global__ __launch_bounds__(256) void lstm_step_k(
    const bf16* __restrict__ Gt,    // [64,4096] precomputed input-side gates
    const bf16* __restrict__ Whh,   // [4096,1024]
    const float* __restrict__ bias, // [4096]
    const bf16* __restrict__ hin,   // [64,1024]
    bf16* __restrict__ hout,        // [64,1024]
    float* __restrict__ c,          // [64,1024] in/out
    float* __restrict__ hf32,       // [64,1024] out
    bf16* __restrict__ Sout)        // [64,1024] or nullptr
{
  __shared__ __attribute__((aligned(16))) bf16 As[64 * 32];
  __shared__ __attribute__((aligned(16))) bf16 Bs[32 * 32];
  __shared__ float gt[64 * 33];
  const int tid = threadIdx.x;
  const int lane = tid & 63;
  const int wave = tid >> 6;
  const int j0 = blockIdx.x * 8;

  f32x4 acc0 = 0, acc1 = 0;
  const int r1 = tid >> 2;
  const int kc = (tid & 3) * 8;
  const int fr = lane & 15;
  const int fk = (lane >> 4) * 8;

  for (int k0 = 0; k0 < 1024; k0 += 32) {
    gload_lds16(hin + (size_t)r1 * 1024 + k0 + kc, As + tid * 8);
    if (tid < 128) {
      int r = tid >> 2;                              // B-tile row = output col 0..31
      int n = (r >> 3) * 1024 + j0 + (r & 7);        // gate*1024 + j
      gload_lds16(Whh + (size_t)n * 1024 + k0 + kc, Bs + tid * 8);
    }
    __syncthreads();
    bf16x8 a = *(const bf16x8*)(As + (wave * 16 + fr) * 32 + fk);
    bf16x8 b0 = *(const bf16x8*)(Bs + fr * 32 + fk);
    bf16x8 b1 = *(const bf16x8*)(Bs + (16 + fr) * 32 + fk);
    acc0 = __builtin_amdgcn_mfma_f32_16x16x32_bf16(a, b0, acc0, 0, 0, 0);
    acc1 = __builtin_amdgcn_mfma_f32_16x16x32_bf16(a, b1, acc1, 0, 0, 0);
    __syncthreads();
  }

  // stage raw gate partial sums to LDS (row = local batch, col = 0..31)
  const int col16 = lane & 15;
  const int rq = (lane >> 4) * 4;
  for (int r = 0; r < 4; ++r) {
    gt[(wave * 16 + rq + r) * 33 + col16] = acc0[r];
    gt[(wave * 16 + rq + r) * 33 + 16 + col16] = acc1[r];
  }
  __syncthreads();

  // cell: 512 (b,jj) pairs
  for (int rep = 0; rep < 2; ++rep) {
    int idx = rep * 256 + tid;
    int b = idx >> 3, jj = idx & 7;
    int j = j0 + jj;
    float gi = gt[b * 33 + jj]      + (float)Gt[(size_t)b * 4096 + j]        + bias[j];
    float gf = gt[b * 33 + 8 + jj]  + (float)Gt[(size_t)b * 4096 + 1024 + j] + bias[1024 + j];
    float gg = gt[b * 33 + 16 + jj] + (float)Gt[(size_t)b * 4096 + 2048 + j] + bias[2048 + j];
    float go = gt[b * 33 + 24 + jj] + (float)Gt[(size_t)b * 4096 + 3072 + j] + bias[3072 + j];
    float cn = sigf(gf) * c[(size_t)b * 1024 + j] + sigf(gi) * tanhf(gg);
    float hn = sigf(go) * tanhf(cn);
    c[(size_t)b * 1024 + j] = cn;
    hf32[(size_t)b * 1024 + j] = hn;
    hout[(size_t)b * 1024 + j] = (bf16)hn;
    if (Sout) Sout[(size_t)b * 1024 + j] = (bf16)hn;
  }
}

// ---------------- host orchestration ----------------
extern "C" void kernel_launch(void* const* d_in, const int* in_sizes, int n_in,
                              void* d_out, int out_size, void* d_ws, size_t ws_size,
                              hipStream_t stream) {
  (void)in_sizes; (void)n_in; (void)out_size; (void)ws_size;
  const float* x      = (const float*)d_in[0];
  const float* dec_c0 = (const float*)d_in[1];
  const float* W_f32[9] = { (const float*)d_in[2],  (const float*)d_in[3],
                            (const float*)d_in[5],  (const float*)d_in[6],
                            (const float*)d_in[8],  (const float*)d_in[9],
                            (const float*)d_in[11], (const float*)d_in[12],
                            (const float*)d_in[14] };
  const float* eb0 = (const float*)d_in[4];
  const float* eb1 = (const float*)d_in[7];
  const float* db0 = (const float*)d_in[10];
  const float* db1 = (const float*)d_in[13];
  const float* fcb = (const float*)d_in[15];
  float* out = (float*)d_out;

  const int B = 64, T = 128, I = 512, H = 1024;
  const int BH = B * H;                       // 65536
  const size_t TBI = (size_t)T * B * I;       // 4194304
  const size_t TBH = (size_t)T * B * H;       // 8388608

  char* p = (char*)d_ws;
  auto alloc = [&](size_t bytes) -> char* {
    char* r = p; p += (bytes + 255) & ~(size_t)255; return r;
  };
  const int wsizes[9] = { 4 * H * I, 4 * H * H, 4 * H * H, 4 * H * H,
                          4 * H * I, 4 * H * H, 4 * H * H, 4 * H * H, I * H };
  bf16* Wbf[9];
  for (int i = 0; i < 9; ++i) Wbf[i] = (bf16*)alloc((size_t)wsizes[i] * 2);
  bf16* xe = (bf16*)alloc(TBI * 2);
  bf16* xd = (bf16*)alloc(TBI * 2);
  bf16* G  = (bf16*)alloc((size_t)T * B * 4 * H * 2);  // 67 MB
  bf16* S0 = (bf16*)alloc(TBH * 2);
  bf16* S1 = (bf16*)alloc(TBH * 2);
  bf16* hb0 = (bf16*)alloc((size_t)BH * 2);
  bf16* hb1 = (bf16*)alloc((size_t)BH * 2);
  float* cst = (float*)alloc((size_t)BH * 4);
  float* hf  = (float*)alloc((size_t)BH * 4);
  float* henc0 = (float*)alloc((size_t)BH * 4);
  float* henc1 = (float*)alloc((size_t)BH * 4);

  for (int i = 0; i < 9; ++i) {
    int n = wsizes[i];
    cast_bf_k<<<(n + 255) / 256, 256, 0, stream>>>(W_f32[i], Wbf[i], n);
  }
  prep_x_k<<<(int)((TBI + 255) / 256), 256, 0, stream>>>(x, xe, xd);

  bf16* hb[2] = { hb0, hb1 };

  // ---- encoder layer 0 ----
  gemm_bt_k<<<dim3(32, 64), 256, 0, stream>>>(xe, Wbf[0], G, nullptr, nullptr, 8192, 4096, 512, 0);
  zero_state_k<<<BH / 256, 256, 0, stream>>>(hb0, cst, BH);
  for (int t = 0; t < T; ++t)
    lstm_step_k<<<128, 256, 0, stream>>>(G + (size_t)t * B * 4096, Wbf[1], eb0,
                                         hb[t & 1], hb[(t + 1) & 1], cst, hf,
                                         S0 + (size_t)t * B * H);
  tanh_save_k<<<BH / 256, 256, 0, stream>>>(hf, henc0, BH);

  // ---- encoder layer 1 ----
  gemm_bt_k<<<dim3(32, 64), 256, 0, stream>>>(S0, Wbf[2], G, nullptr, nullptr, 8192, 4096, 1024, 0);
  zero_state_k<<<BH / 256, 256, 0, stream>>>(hb0, cst, BH);
  for (int t = 0; t < T; ++t)
    lstm_step_k<<<128, 256, 0, stream>>>(G + (size_t)t * B * 4096, Wbf[3], eb1,
                                         hb[t & 1], hb[(t + 1) & 1], cst, hf, nullptr);
  tanh_save_k<<<BH / 256, 256, 0, stream>>>(hf, henc1, BH);

  // ---- decoder layer 0 ----
  gemm_bt_k<<<dim3(32, 64), 256, 0, stream>>>(xd, Wbf[4], G, nullptr, nullptr, 8192, 4096, 512, 0);
  dec_init_k<<<BH / 256, 256, 0, stream>>>(henc0, dec_c0, hb0, cst, BH);
  for (int t = 0; t < T; ++t)
    lstm_step_k<<<128, 256, 0, stream>>>(G + (size_t)t * B * 4096, Wbf[5], db0,
                                         hb[t & 1], hb[(t + 1) & 1], cst, hf,
                                         S0 + (size_t)t * B * H);

  // ---- decoder layer 1 ----
  gemm_bt_k<<<dim3(32, 64), 256, 0, stream>>>(S0, Wbf[6], G, nullptr, nullptr, 8192, 4096, 1024, 0);
  dec_init_k<<<BH / 256, 256, 0, stream>>>(henc1, dec_c0 + BH, hb0, cst, BH);
  for (int t = 0; t < T; ++t)
    lstm_step_k<<<128, 256, 0, stream>>>(G + (size_t)t * B * 4096, Wbf[7], db1,
                                         hb[t & 1], hb[(t + 1) & 1], cst, hf,
                                         S1 + (size_t)t * B * H);

  // ---- FC: sigmoid(S1 @ fcW^T + fcb), permute [t,b]->[b,t] ----
  gemm_bt_k<<<dim3(4, 64), 256, 0, stream>>>(S1, Wbf[8], nullptr, out, fcb, 8192, 512, 1024, 1);
}